// Round 1
// 465.952 us; speedup vs baseline: 1.2306x; 1.2306x over previous
//
#include <hip/hip_runtime.h>

#define LSEQ 1024
#define NDIM 256

// output layout (floats): c_all | y_all | GBT_A | GBT_B
#define O_C 0
#define O_Y (LSEQ * NDIM)                      // 262144
#define O_A (O_Y + LSEQ)                       // 263168
#define O_B (O_A + (size_t)LSEQ * NDIM * NDIM) // 67372032

typedef float v4f __attribute__((ext_vector_type(4)));

static __device__ __forceinline__ float frcp(float x) {
    return __builtin_amdgcn_rcpf(x);
}

// wave-wide shift-right-by-1 via DPP (VALU, no DS pipe).
// lane l gets src from lane l-1; lane 0 gets `inject`.
static __device__ __forceinline__ float dpp_shr1(float inject, float src) {
    int r = __builtin_amdgcn_update_dpp(
        __float_as_int(inject), __float_as_int(src),
        0x138 /* WAVE_SHR1 */, 0xF, 0xF, false);
    return __int_as_float(r);
}

// Opaque register copies. The compiler cannot copy-propagate through these,
// so store data is guaranteed to live in registers DISTINCT from the scan
// state (cc/yacc) that gets rewritten every tick. Combined with the
// group-end liveness asm below, each tick's store data stays in its own
// registers until ~8 ticks after the store issued -> the s_waitcnt the
// compiler inserts before redefining store-data VGPRs (VMEM store WAR
// hazard) is already satisfied -> no per-tick ~600-cycle store-retire stall.
static __device__ __forceinline__ v4f stage4(float a, float b, float c, float d) {
    float x0, x1, x2, x3;
    asm volatile("v_mov_b32 %0, %4\n\t"
                 "v_mov_b32 %1, %5\n\t"
                 "v_mov_b32 %2, %6\n\t"
                 "v_mov_b32 %3, %7"
                 : "=&v"(x0), "=&v"(x1), "=&v"(x2), "=&v"(x3)
                 : "v"(a), "v"(b), "v"(c), "v"(d));
    v4f r; r.x = x0; r.y = x1; r.z = x2; r.w = x3;
    return r;
}
static __device__ __forceinline__ float stage1(float a) {
    float x;
    asm volatile("v_mov_b32 %0, %1" : "=&v"(x) : "v"(a));
    return x;
}

__global__ __launch_bounds__(256) void hippo_main(
    const float* __restrict__ f,
    const float* __restrict__ init_state,
    const float* __restrict__ Bvec,   // = r_i = sqrt(2i+1), bit-exact vs reference
    float* __restrict__ out)
{
    const int tid = threadIdx.x;
    const int bid = blockIdx.x;

    if (bid == 0) {
        // ================= sequential scan: systolic over 64 lanes ==========
        // lane l owns elements i = 4l..4l+3. At tick t, lane l performs
        // recurrence step k0 = t - l. Scan state flows lane -> lane+1 each
        // tick via DPP wave_shr1. Store data is staged 8 deep in rotating
        // registers (see stage4/stage1) so the per-tick global_store never
        // forces a store-retire wait on the scan wave.
        if (tid >= 64) return;
        const int l = tid;
        float rr[4], cc[4];
        #pragma unroll
        for (int e = 0; e < 4; ++e) {
            rr[e] = Bvec[4 * l + e];
            cc[e] = init_state[4 * l + e];
        }
        const float base1 = (float)(4 * l + 1);  // (i+1) for e=0

        float T = 0.0f, S = 0.0f, ssf = 0.0f, yacc = 0.0f;
        // f staged in 64-wide register chunks, rotated every 64 ticks
        float fcur = f[l];
        float fnxt = (64 + l < LSEQ) ? f[64 + l] : 0.0f;

        float* cout = out + O_C;
        float* yout = out + O_Y;

        // 8-deep store staging buffers (one set per tick of the unrolled group)
        v4f   cvb[8];
        float yb[8];
        #pragma unroll
        for (int g = 0; g < 8; ++g) { cvb[g] = (v4f){0.f, 0.f, 0.f, 0.f}; yb[g] = 0.0f; }

        for (int tb = 0; tb < LSEQ + 64; tb += 8) {   // ticks tb .. tb+7
            // f-chunk rotation (tb is a multiple of 8; 64 | tb exactly at the
            // original rotation ticks)
            if ((tb & 63) == 0 && tb) {
                fcur = fnxt;
                int idx = tb + 64 + l;
                fnxt = (idx < LSEQ) ? f[idx] : 0.0f;
            }
            const int fb = tb & 63;

            #pragma unroll
            for (int g = 0; g < 8; ++g) {
                const int t = tb + g;
                // f[t] broadcast: uniform lane index -> scalar readlane (no DS)
                float ft = __int_as_float(
                    __builtin_amdgcn_readlane(__float_as_int(fcur), fb + g));

                const int k0 = t - l;
                const float h  = 0.5f * frcp((float)(k0 + 1));   // lane's ss/2
                const float h0 = 0.5f * frcp((float)(t + 1));    // lane 0's ss/2
                const float ssf0 = 2.0f * h0 * ft;               // ss_t * f_t

                // pipeline handoff (unconditional, all 64 lanes active)
                T    = dpp_shr1(0.0f, T);
                S    = dpp_shr1(0.0f, S);
                yacc = dpp_shr1(0.0f, yacc);
                ssf  = dpp_shr1(ssf0, ssf);

                if (k0 >= 0 && k0 < LSEQ) {
                    #pragma unroll
                    for (int e = 0; e < 4; ++e) {
                        float d    = fmaf(h, base1 + (float)e, 1.0f); // 1 + h(i+1)
                        float invd = frcp(d);
                        // w = (2-d)*c + r*(ssf - h*T)   [P2 row + forcing]
                        float w = fmaf(2.0f - d, cc[e], rr[e] * fmaf(-h, T, ssf));
                        T = fmaf(rr[e], cc[e], T);
                        // forward substitution: c_new = (w - h*r*S)/d
                        float num = fmaf(-h * rr[e], S, w);
                        float cn  = num * invd;
                        S = fmaf(rr[e], cn, S);
                        cc[e] = cn;
                    }
                    yacc += (cc[0] + cc[1]) + (cc[2] + cc[3]);
                    // stage through opaque copies, then store the staged regs
                    cvb[g] = stage4(cc[0], cc[1], cc[2], cc[3]);
                    *reinterpret_cast<v4f*>(cout + (size_t)k0 * NDIM + 4 * l) = cvb[g];
                    yb[g] = stage1(yacc);
                    if (l == 63) yout[k0] = yb[g];
                }
            }
            // Liveness anchor: read ALL 8 stage sets here so they occupy
            // distinct registers for the whole group. A stage register is
            // first redefined 8 ticks after its store issued, by which time
            // the store has retired -> the inserted waitcnt is free.
            asm volatile("" ::
                "v"(cvb[0]), "v"(cvb[1]), "v"(cvb[2]), "v"(cvb[3]),
                "v"(cvb[4]), "v"(cvb[5]), "v"(cvb[6]), "v"(cvb[7]),
                "v"(yb[0]), "v"(yb[1]), "v"(yb[2]), "v"(yb[3]),
                "v"(yb[4]), "v"(yb[5]), "v"(yb[6]), "v"(yb[7]));
        }
    } else {
        // ================= GBT_A / GBT_B for k = bid-1 ======================
        // P1 = I - h A lower-triangular semiseparable; M = P1^{-1} has
        // M[i,i] = 1/d_i, M[i,j] = -h r_i r_j/(d_i d_j) * prod_{m=j+1}^{i-1} g_m,
        // g_m = (1 - h m)/d_m.  Ad = 2M - I.
        const int k = bid - 1;
        const int lane = tid & 63;
        const int wave = tid >> 6;
        const float kp = (float)(k + 1);
        const float ss = 1.0f / kp;
        const float h  = 0.5f * ss;

        __shared__ float s_r[NDIM], s_invd[NDIM], s_rowco[NDIM], s_g[NDIM], s_diag[NDIM];
        {
            int i = tid;                           // 256 threads, 256 elements
            float r    = Bvec[i];
            float d    = fmaf(h, (float)(i + 1), 1.0f);
            float invd = 1.0f / d;
            s_r[i]     = r;
            s_invd[i]  = invd;
            s_rowco[i] = -2.0f * h * r * invd;     // 2 * (-h r_i / d_i)
            s_g[i]     = (1.0f - h * (float)i) * invd;
            s_diag[i]  = fmaf(2.0f, invd, -1.0f);  // 2/d_i - 1
        }
        __syncthreads();

        // ---- GBT_B, closed form (replaces the serial tid==0 substitution):
        // Sb_i = (ss/h)(1 - Pi_i) solves the recurrence, hence
        //   Bd_i = ss * r_i * invd_i * prod_{j<i} g_j.
        // 256 threads, one output each; issued early so the store overlaps
        // the A-row walk below.
        {
            float Pi = 1.0f;
            for (int j = 0; j < NDIM - 1; ++j) {
                float gj = s_g[j];                 // uniform LDS broadcast
                Pi *= (j < tid) ? gj : 1.0f;
            }
            float* outB = out + O_B + (size_t)k * NDIM;
            outB[tid] = ss * s_r[tid] * s_invd[tid] * Pi;
        }

        // lane owns columns j = 4*lane..4*lane+3; per-column running state
        float colc[4], Scol[4] = {0.f, 0.f, 0.f, 0.f};
        #pragma unroll
        for (int e = 0; e < 4; ++e) {
            int j = 4 * lane + e;
            colc[e] = s_r[j] * s_invd[j];          // start value when row passes j
        }

        const int i0 = wave * 64;
        // ---- recurrence-only rows [0, i0): advance column state, no stores
        for (int i = 0; i < i0; ++i) {
            float g = s_g[i];
            #pragma unroll
            for (int e = 0; e < 4; ++e) {
                int j = 4 * lane + e;
                if (j < i)       Scol[e] *= g;
                else if (j == i) Scol[e] = colc[e];
            }
        }
        // ---- owned rows [i0, i0+64): compute + nontemporal store
        float* outA = out + O_A + (size_t)k * (NDIM * NDIM) + 4 * lane;
        for (int i = i0; i < i0 + 64; ++i) {
            float rowco = s_rowco[i];
            float g     = s_g[i];
            float dg    = s_diag[i];
            float v[4];
            #pragma unroll
            for (int e = 0; e < 4; ++e) {
                int j = 4 * lane + e;
                if (j < i) {
                    v[e] = rowco * Scol[e];
                    Scol[e] *= g;
                } else if (j == i) {
                    v[e] = dg;
                    Scol[e] = colc[e];
                } else {
                    v[e] = 0.0f;
                }
            }
            v4f vv = { v[0], v[1], v[2], v[3] };
            __builtin_nontemporal_store(
                vv, reinterpret_cast<v4f*>(outA + (size_t)i * NDIM));
        }
    }
}

extern "C" void kernel_launch(void* const* d_in, const int* in_sizes, int n_in,
                              void* d_out, int out_size, void* d_ws, size_t ws_size,
                              hipStream_t stream) {
    (void)in_sizes; (void)n_in; (void)d_ws; (void)ws_size; (void)out_size;
    const float* f    = (const float*)d_in[0];
    const float* init = (const float*)d_in[1];
    const float* Bv   = (const float*)d_in[3];   // B = r[:,None]
    float* outp       = (float*)d_out;
    hippo_main<<<1 + LSEQ, 256, 0, stream>>>(f, init, Bv, outp);
}